// Round 10
// baseline (1052.894 us; speedup 1.0000x reference)
//
#include <hip/hip_runtime.h>
#include <math.h>

namespace {

typedef __bf16 bf16_t;
typedef bf16_t bf16x8 __attribute__((ext_vector_type(8)));
typedef float floatx4 __attribute__((ext_vector_type(4)));

constexpr int kN = 1024;      // tokens
constexpr int kM = 64;        // multiplicity
constexpr int kP = 64;        // PE dim
constexpr float kEps = 1e-5f;
constexpr int kFN = 1024;     // FFT length
constexpr size_t kYOFF = 16777216;   // ybf plane stride (bf16 elems)

__device__ __forceinline__ float sigmoidf(float v) { return 1.0f / (1.0f + expf(-v)); }

__device__ __forceinline__ floatx4 mfma16(bf16x8 a, bf16x8 b, floatx4 c) {
  return __builtin_amdgcn_mfma_f32_16x16x32_bf16(a, b, c, 0, 0, 0);
}

// 3-term split product: acc += (ah+al)*(bh+bl) dropping al*bl
// REQUIRED for residual-stream h inputs (hi-only h at GEMM input fails: r14, 1.8e-2)
__device__ __forceinline__ void fma3(floatx4& acc, bf16x8 ah, bf16x8 al,
                                     bf16x8 bh, bf16x8 bl) {
  acc = mfma16(ah, bh, acc);
  acc = mfma16(ah, bl, acc);
  acc = mfma16(al, bh, acc);
}

// 2-term: exact split weights x bf16-rounded activation (safe for hyena-branch only)
__device__ __forceinline__ void fma2(floatx4& acc, bf16x8 ah, bf16x8 bh, bf16x8 bl) {
  acc = mfma16(ah, bh, acc);
  acc = mfma16(ah, bl, acc);
}

union U4 { uint4 u; bf16_t b[8]; };
union Pk4 { uint2 u; bf16_t b[4]; };
union Ub2 { uint u; bf16_t b[2]; };

// async 16B/lane global->LDS DMA (wave-uniform LDS base + lane*16 scatter)
// NOTE (r1/r2): k_qkv keeps the r0 single-buffer stage->sync->compute structure at
// 40KB LDS. B-direct-to-reg pollutes the vmcnt queue (r1, +9us); 80KB dbuf loses
// cross-block overlap (r2, +23us). Cross-block wave overlap at 3-4 blocks/CU is the
// latency hider.
// r3/r4 control: identical k_qkv = 118 (r0/r4/r8) vs 142 (r3/r6) with identical
// bytes -> ~20% cross-session clock variance; k_qkv compute structure is FROZEN.
// r5: NEVER funnel per-block stats through same-line device atomics (131K atomicAdds
// on one 512B region = +420us; plain stores + reduce kernel wins).
// r7/r9: k_mix+k_reg fusion failed correctness TWICE (0.478 / 0.485) -- alias theory
// falsified by r9 (ybf fully disjoint, same failure). Bug never located by
// inspection; fusion is PERMANENTLY SHELVED. r10 takes the traffic win differently:
// retile k_reg to 64x256 so each hsh strip stages once (was 4x).
__device__ __forceinline__ void glds16(const bf16_t* g, bf16_t* l) {
  __builtin_amdgcn_global_load_lds(
      (const __attribute__((address_space(1))) void*)g,
      (__attribute__((address_space(3))) void*)l, 16, 0, 0);
}

// hsh fragment-major index for (row r, 8-elem group d8), hi plane (lo = +512)
__device__ __forceinline__ size_t hidx(int r, int d8) {
  const int rb = r >> 6, rr = r & 63;
  return (size_t)(rb * 8 + (d8 >> 2)) * 4096 + (rr >> 4) * 1024 + (d8 & 3) * 128 + (rr & 15) * 8;
}

// padded LDS index for FFT work array (breaks small-span bank conflicts)
__device__ __forceinline__ int zi(int i) { return i + (i >> 4); }

__device__ __forceinline__ float2 cadd(float2 a, float2 b) { return {a.x + b.x, a.y + b.y}; }
__device__ __forceinline__ float2 csub(float2 a, float2 b) { return {a.x - b.x, a.y - b.y}; }
__device__ __forceinline__ float2 cmul(float2 a, float2 w) {
  return {a.x * w.x - a.y * w.y, a.x * w.y + a.y * w.x};
}
__device__ __forceinline__ float2 cmulc(float2 a, float2 w) {   // a * conj(w)
  return {a.x * w.x + a.y * w.y, a.y * w.x - a.x * w.y};
}

// ---------------------------------------------------------------- init
__global__ void k_s0(const float* __restrict__ tok_emb, const float* __restrict__ Wf,
                     float* __restrict__ s0) {
  __shared__ float f[kP];
  const int n = blockIdx.x;
  const int t = threadIdx.x;                       // 64 threads
  const int tt = (n == kN - 1) ? 2 : (n & 1);
  const int j = t >> 1;
  const float cexp = (float)(-9.210340371976184 / 64.0);   // -ln(10000)/P
  const float divj = expf((float)(2 * j) * cexp);
  const float ang = (float)n * divj;
  const float pe = (t & 1) ? cosf(ang) : sinf(ang);
  f[t] = pe + tok_emb[tt * kP + t];
  __syncthreads();
  float acc = 0.0f;
#pragma unroll 8
  for (int p = 0; p < kP; ++p) acc = fmaf(f[p], Wf[p * kM + t], acc);
  s0[n * kM + t] = acc;
}

// h planes (fragment-major): irreps m0=d8*2, m1=m0+1 per thread
__global__ void k_h0(const float* __restrict__ x, const float* __restrict__ wv,
                     const float* __restrict__ s0, bf16_t* __restrict__ hsh) {
  const int idx = blockIdx.x * 256 + threadIdx.x;  // r*32 + d8
  const int r = idx >> 5, d8 = idx & 31;
  const int n = r & (kN - 1);
  const int m0 = d8 * 2, m1 = m0 + 1;
  const float w0 = wv[m0], w1 = wv[m1];
  const float x0 = x[r * 3 + 0], x1 = x[r * 3 + 1], x2 = x[r * 3 + 2];
  float f[8];
  f[0] = s0[n * kM + m0]; f[1] = x0 * w0; f[2] = x1 * w0; f[3] = x2 * w0;
  f[4] = s0[n * kM + m1]; f[5] = x0 * w1; f[6] = x1 * w1; f[7] = x2 * w1;
  U4 oh, ol;
#pragma unroll
  for (int i = 0; i < 8; ++i) {
    const bf16_t h_ = (bf16_t)f[i];
    oh.b[i] = h_; ol.b[i] = (bf16_t)(f[i] - (float)h_);
  }
  const size_t base = hidx(r, d8);
  *(uint4*)(hsh + base) = oh.u;
  *(uint4*)(hsh + base + 512) = ol.u;
}

// ---------------------------------------------------------------- weight prep (batched, all 3 layers)
__global__ void k_wqkv3(const float* __restrict__ Wq0, const float* __restrict__ Wk0,
                        const float* __restrict__ Wv0,
                        const float* __restrict__ Wq1, const float* __restrict__ Wk1,
                        const float* __restrict__ Wv1,
                        const float* __restrict__ Wq2, const float* __restrict__ Wk2,
                        const float* __restrict__ Wv2, bf16_t* __restrict__ wall3) {
  const int l = blockIdx.y;
  const int H = (l == 2) ? 160 : 360;
  const int gy = (l == 2) ? 3 : 6;
  const int c = blockIdx.x;    // 0..383
  if (c >= gy * 64) return;
  const int k = threadIdx.x;   // 0..255
  const float* Wq = (l == 0) ? Wq0 : ((l == 1) ? Wq1 : Wq2);
  const float* Wk = (l == 0) ? Wk0 : ((l == 1) ? Wk1 : Wk2);
  const float* Wv = (l == 0) ? Wv0 : ((l == 1) ? Wv1 : Wv2);
  bf16_t* wall = wall3 + ((l == 2) ? 1179648 : (size_t)l * 589824);
  const bool ok = c < H;
  const float w[3] = {ok ? Wq[k * H + c] : 0.f, ok ? Wk[k * H + c] : 0.f,
                      ok ? Wv[k * H + c] : 0.f};
  const int ct = c >> 6, cgrp = (c >> 4) & 3, cl = c & 15;
  const int kc = k >> 5, quad = (k >> 3) & 3, off = k & 7;
  const size_t base = (size_t)(ct * 8 + kc) * 12288 + cgrp * 512 + quad * 128 + cl * 8 + off;
#pragma unroll
  for (int mat = 0; mat < 3; ++mat) {
    const bf16_t hi = (bf16_t)w[mat];
    wall[base + mat * 4096] = hi;
    wall[base + mat * 4096 + 2048] = (bf16_t)(w[mat] - (float)hi);
  }
}

__global__ void k_wo3(const float* __restrict__ Wo0, const float* __restrict__ Wo1,
                      const float* __restrict__ Wo2, bf16_t* __restrict__ WoF3) {
  const int l = blockIdx.y;
  const int H = (l == 2) ? 160 : 360;
  const float* Wo = (l == 0) ? Wo0 : ((l == 1) ? Wo1 : Wo2);
  bf16_t* WoF = WoF3 + (size_t)l * 196608;
  const int d = blockIdx.x;    // 0..255
  const int c = threadIdx.x;   // 0..383
  const float w = (c < H) ? Wo[c * 256 + d] : 0.f;
  const int dt = d >> 6, dgrp = (d >> 4) & 3, dl = d & 15;
  const int kc = c >> 5, quad = (c >> 3) & 3, off = c & 7;
  const size_t base = (size_t)(dt * 12 + kc) * 4096 + dgrp * 512 + quad * 128 + dl * 8 + off;
  const bf16_t hi = (bf16_t)w;
  WoF[base] = hi;
  WoF[base + 2048] = (bf16_t)(w - (float)hi);
}

__global__ void k_bt3(const float* __restrict__ W00, const float* __restrict__ W10,
                      const float* __restrict__ W01, const float* __restrict__ W11,
                      const float* __restrict__ W02, const float* __restrict__ W12,
                      bf16_t* __restrict__ BtF3) {
  const int l = blockIdx.y;
  const float* W0 = (l == 0) ? W00 : ((l == 1) ? W01 : W02);
  const float* W1 = (l == 0) ? W10 : ((l == 1) ? W11 : W12);
  bf16_t* BtF = BtF3 + (size_t)l * 131072;
  const int col = blockIdx.x, row = threadIdx.x;
  const int k = col >> 2, ck = col & 3, m = row >> 2, cm = row & 3;
  float v = 0.f;
  if (cm == ck) v = (ck == 0 ? W0 : W1)[m * 64 + k];
  const int ct = col >> 6, cgrp = (col >> 4) & 3, cl = col & 15;
  const int kc = row >> 5, quad = (row >> 3) & 3, off = row & 7;
  const size_t base = (size_t)(ct * 8 + kc) * 4096 + cgrp * 512 + quad * 128 + cl * 8 + off;
  const bf16_t hi = (bf16_t)v;
  BtF[base] = hi;
  BtF[base + 2048] = (bf16_t)(v - (float)hi);
}

// ---------------------------------------------------------------- FFT (fused radix-2 pairs)
__global__ void k_tw(float2* __restrict__ twg) {
  const int j = blockIdx.x * 256 + threadIdx.x;
  if (j < kFN / 2) {
    float s, c;
    sincosf(-6.283185307179586f * (float)j / (float)kFN, &s, &c);
    twg[j].x = c; twg[j].y = s;
  }
}

// forward DIF radix-4 step (two radix-2 stages fused), one array
__device__ __forceinline__ void dif_step(float2* z, const float2* tw, int m, int p) {
  const int pm = p & (m - 1);
  const int j = ((p & ~(m - 1)) << 2) | pm;
  const int tm2 = 512 / (2 * m), tm1 = 512 / m;
  const float2 x0 = z[zi(j)], x1 = z[zi(j + m)];
  const float2 x2 = z[zi(j + 2 * m)], x3 = z[zi(j + 3 * m)];
  const float2 w2 = tw[pm * tm2], w2b = tw[(pm + m) * tm2], w1 = tw[pm * tm1];
  const float2 a0 = cadd(x0, x2), a2 = cmul(csub(x0, x2), w2);
  const float2 a1 = cadd(x1, x3), a3 = cmul(csub(x1, x3), w2b);
  z[zi(j)]         = cadd(a0, a1);
  z[zi(j + m)]     = cmul(csub(a0, a1), w1);
  z[zi(j + 2 * m)] = cadd(a2, a3);
  z[zi(j + 3 * m)] = cmul(csub(a2, a3), w1);
}

// inverse DIT radix-4 step (fused), one array
__device__ __forceinline__ void dit_step(float2* z, const float2* tw, int m, int p) {
  const int pm = p & (m - 1);
  const int j = ((p & ~(m - 1)) << 2) | pm;
  const int tm2 = 512 / (2 * m), tm1 = 512 / m;
  const float2 x0 = z[zi(j)], x1 = z[zi(j + m)];
  const float2 x2 = z[zi(j + 2 * m)], x3 = z[zi(j + 3 * m)];
  const float2 w1 = tw[pm * tm1], w2 = tw[pm * tm2], w2b = tw[(pm + m) * tm2];
  const float2 c1 = cmulc(x1, w1), c3 = cmulc(x3, w1);
  const float2 b0 = cadd(x0, c1), b1 = csub(x0, c1);
  const float2 b2 = cadd(x2, c3), b3 = csub(x2, c3);
  const float2 d2 = cmulc(b2, w2), d3 = cmulc(b3, w2b);
  z[zi(j)]         = cadd(b0, d2);
  z[zi(j + 2 * m)] = csub(b0, d2);
  z[zi(j + m)]     = cadd(b1, d3);
  z[zi(j + 3 * m)] = csub(b1, d3);
}

// forward DIF, natural in -> bit-reversed out (single array, for k_kf3)
__device__ void fft_dif(float2* z, const float2* tw) {
  const int p = threadIdx.x;
#pragma unroll
  for (int m = 256; m >= 1; m >>= 2) {
    __syncthreads();
    dif_step(z, tw, m, p);
  }
}

// dual-array PARTIAL transforms for k_conv.
// r4: m=1 (both dirs) + pointwise fused in-register (exact twiddles).
// r5: m=256 fwd level fused with the LOAD (in-register, twiddles from global).
__device__ void fft_dif2_hi(float2* za, float2* zb, const float2* tw) {
  const int p = threadIdx.x;
#pragma unroll
  for (int m = 64; m >= 4; m >>= 2) {
    __syncthreads();
    dif_step(za, tw, m, p);
    dif_step(zb, tw, m, p);
  }
}

__device__ void fft_dit_inv2_hi(float2* za, float2* zb, const float2* tw) {
  const int p = threadIdx.x;
#pragma unroll
  for (int m = 4; m <= 256; m <<= 2) {
    __syncthreads();
    dit_step(za, tw, m, p);
    dit_step(zb, tw, m, p);
  }
}

// filter spectra for ALL layers, DIF (bit-reversed) order; 880 blocks
__global__ __launch_bounds__(256) void k_kf3(const float* __restrict__ f0,
    const float* __restrict__ f1, const float* __restrict__ f2,
    const float2* __restrict__ twg, float2* __restrict__ kf3) {
  __shared__ float2 z[kFN + kFN / 16];
  __shared__ float2 tw[kFN / 2];
  const int bid = blockIdx.x;
  const int l = (bid < 360) ? 0 : ((bid < 720) ? 1 : 2);
  const int c = bid - ((l == 0) ? 0 : ((l == 1) ? 360 : 720));
  const int H = (l == 2) ? 160 : 360;
  const float* filt = (l == 0) ? f0 : ((l == 1) ? f1 : f2);
  float2* kf = kf3 + (size_t)l * 368640;
  for (int j = threadIdx.x; j < kFN / 2; j += 256) tw[j] = twg[j];
  for (int n = threadIdx.x; n < kFN; n += 256) {
    z[zi(n)].x = filt[n * H + c];
    z[zi(n)].y = 0.0f;
  }
  fft_dif(z, tw);
  __syncthreads();
  for (int j = threadIdx.x; j < kFN; j += 256) kf[c * kFN + j] = z[zi(j)];
}

// packed circular conv + fused q-product; bf16 in, fp32 FFT, bf16 prod out
// r3: FOUR sequences per block; r4: m=1+pointwise fused; r5: m=256 fused with load.
__global__ __launch_bounds__(256) void k_conv(const bf16_t* __restrict__ kvb,
    const bf16_t* __restrict__ qb, bf16_t* __restrict__ prodb,
    const float2* __restrict__ kf, const float2* __restrict__ twg, int H) {
  __shared__ float2 za[kFN + kFN / 16];
  __shared__ float2 zb[kFN + kFN / 16];
  __shared__ float2 tw[kFN / 2];
  const int blk = blockIdx.x;              // pb*H + c, pb in 0..15 (4 batches each)
  const int c = blk % H;
  const int pb = blk / H;
  const size_t off0 = ((size_t)((4 * pb) * H + c)) << 10;
  const size_t off1 = ((size_t)((4 * pb + 1) * H + c)) << 10;
  const size_t off2 = ((size_t)((4 * pb + 2) * H + c)) << 10;
  const size_t off3 = ((size_t)((4 * pb + 3) * H + c)) << 10;
  for (int j = threadIdx.x; j < kFN / 2; j += 256) tw[j] = twg[j];
  {
    const int p = threadIdx.x;
    float2 xa[4], xb[4];
#pragma unroll
    for (int e = 0; e < 4; ++e) {
      const int idx = p + e * 256;
      xa[e].x = (float)kvb[off0 + idx]; xa[e].y = (float)kvb[off1 + idx];
      xb[e].x = (float)kvb[off2 + idx]; xb[e].y = (float)kvb[off3 + idx];
    }
    // dif m=256: tm2=1, tm1=2; twiddles straight from global (L2-hot)
    const float2 w2 = twg[p], w2b = twg[p + 256], w1 = twg[2 * p];
#pragma unroll
    for (int arr = 0; arr < 2; ++arr) {
      float2* z = arr ? zb : za;
      const float2* x = arr ? xb : xa;
      const float2 a0 = cadd(x[0], x[2]), a2 = cmul(csub(x[0], x[2]), w2);
      const float2 a1 = cadd(x[1], x[3]), a3 = cmul(csub(x[1], x[3]), w2b);
      z[zi(p)]       = cadd(a0, a1);
      z[zi(p + 256)] = cmul(csub(a0, a1), w1);
      z[zi(p + 512)] = cadd(a2, a3);
      z[zi(p + 768)] = cmul(csub(a2, a3), w1);
    }
  }
  fft_dif2_hi(za, zb, tw);                 // levels m=64..4
  __syncthreads();
  {
    const int p = threadIdx.x;             // owns elems 4p..4p+3 of both arrays
    const float2 B0 = kf[c * kFN + 4 * p + 0];
    const float2 B1 = kf[c * kFN + 4 * p + 1];
    const float2 B2 = kf[c * kFN + 4 * p + 2];
    const float2 B3 = kf[c * kFN + 4 * p + 3];
#pragma unroll
    for (int arr = 0; arr < 2; ++arr) {
      float2* z = arr ? zb : za;
      const float2 x0 = z[zi(4 * p)], x1 = z[zi(4 * p + 1)];
      const float2 x2 = z[zi(4 * p + 2)], x3 = z[zi(4 * p + 3)];
      // dif m=1 (w2={1,0}, w2b={0,-1}, w1={1,0} -- exact)
      const float2 a0 = cadd(x0, x2), a2 = csub(x0, x2);
      const float2 a1 = cadd(x1, x3), dd = csub(x1, x3);
      const float2 a3 = {dd.y, -dd.x};
      const float2 y0 = cadd(a0, a1), y1 = csub(a0, a1);
      const float2 y2 = cadd(a2, a3), y3 = csub(a2, a3);
      // pointwise
      const float2 o0 = cmul(y0, B0), o1 = cmul(y1, B1);
      const float2 o2 = cmul(y2, B2), o3 = cmul(y3, B3);
      // dit m=1 (w1={1,0}, w2={1,0}, w2b={0,-1} -- exact)
      const float2 t0 = cadd(o0, o1), t1 = csub(o0, o1);
      const float2 t2 = cadd(o2, o3), t3 = csub(o2, o3);
      const float2 d3 = {-t3.y, t3.x};
      z[zi(4 * p)]     = cadd(t0, t2);
      z[zi(4 * p + 2)] = csub(t0, t2);
      z[zi(4 * p + 1)] = cadd(t1, d3);
      z[zi(4 * p + 3)] = csub(t1, d3);
    }
  }
  fft_dit_inv2_hi(za, zb, tw);             // levels m=4..256
  __syncthreads();
  const float s = 1.0f / (float)kFN;
  for (int n2 = threadIdx.x; n2 < 512; n2 += 256) {
    Ub2 q0, q1, q2, q3, o0, o1, o2, o3;
    q0.u = *(const uint*)(qb + off0 + 2 * n2);
    q1.u = *(const uint*)(qb + off1 + 2 * n2);
    q2.u = *(const uint*)(qb + off2 + 2 * n2);
    q3.u = *(const uint*)(qb + off3 + 2 * n2);
    o0.b[0] = (bf16_t)((za[zi(2 * n2)].x * s) * (float)q0.b[0]);
    o0.b[1] = (bf16_t)((za[zi(2 * n2 + 1)].x * s) * (float)q0.b[1]);
    o1.b[0] = (bf16_t)((za[zi(2 * n2)].y * s) * (float)q1.b[0]);
    o1.b[1] = (bf16_t)((za[zi(2 * n2 + 1)].y * s) * (float)q1.b[1]);
    o2.b[0] = (bf16_t)((zb[zi(2 * n2)].x * s) * (float)q2.b[0]);
    o2.b[1] = (bf16_t)((zb[zi(2 * n2 + 1)].x * s) * (float)q2.b[1]);
    o3.b[0] = (bf16_t)((zb[zi(2 * n2)].y * s) * (float)q3.b[0]);
    o3.b[1] = (bf16_t)((zb[zi(2 * n2 + 1)].y * s) * (float)q3.b[1]);
    *(uint*)(prodb + off0 + 2 * n2) = o0.u;
    *(uint*)(prodb + off1 + 2 * n2) = o1.u;
    *(uint*)(prodb + off2 + 2 * n2) = o2.u;
    *(uint*)(prodb + off3 + 2 * n2) = o3.u;
  }
}

// ---------------------------------------------------------------- GEMM 1 (split MFMA, LDS-DMA): q/k/v
// 128x64 tile (2 rb per block), XCD-swizzled; h enters split hi/lo (fma3); bf16 outputs
// FROZEN r0 structure (measured best): single 40KB buffer, stage->sync->compute->sync.
__global__ __launch_bounds__(256) void k_qkv(const bf16_t* __restrict__ hsh,
    const bf16_t* __restrict__ wall, int H,
    bf16_t* __restrict__ qtb, bf16_t* __restrict__ kvb) {
  __shared__ bf16_t lds[20480];            // 40 KB: A0 8K + A1 8K + B 24K
  const int gy = (H + 63) >> 6;
  const int bid = blockIdx.x;
  const int xcd = bid & 7, sseq = bid >> 3;
  const int ct = sseq % gy;
  const int rb2 = (sseq / gy) * 8 + xcd;
  const int rb0 = rb2 * 2, rb1 = rb0 + 1;
  const int t = threadIdx.x;
  const int lane = t & 63, wave = t >> 6;
  const int l15 = lane & 15, quad = lane >> 4;
  const int c0 = ct * 64;
  const int wr = (wave & 1) * 32, wc = (wave >> 1) * 32;
  const int wr16 = (wave & 1) * 2, wc16 = (wave >> 1) * 2;
  const int q128l = quad * 128 + l15 * 8;
  floatx4 aq[2][2][2] = {}, ak_[2][2][2] = {}, av_[2][2][2] = {};   // [rbx][i][j]
  for (int kt = 0; kt < 8; ++kt) {
    {
      const bf16_t* A0 = hsh + (size_t)(rb0 * 8 + kt) * 4096;
      const bf16_t* A1 = hsh + (size_t)(rb1 * 8 + kt) * 4096;
      const bf16_t* Bs = wall + (size_t)(ct * 8 + kt) * 12288;
#pragma unroll
      for (int s = 0; s < 10; ++s) {
        const int seg = wave * 10 + s;
        const bf16_t* src = (seg < 8) ? (A0 + seg * 512)
                          : (seg < 16) ? (A1 + (seg - 8) * 512)
                                       : (Bs + (seg - 16) * 512);
        glds16(src + lane * 8, &lds[seg * 512]);
      }
    }
    __syncthreads();
    bf16x8 ah[2][2], al[2][2];             // [rbx][i]
#pragma unroll
    for (int rbx = 0; rbx < 2; ++rbx)
#pragma unroll
      for (int i = 0; i < 2; ++i) {
        ah[rbx][i] = *(const bf16x8*)(lds + rbx * 4096 + ((wr16 + i) * 2 + 0) * 512 + q128l);
        al[rbx][i] = *(const bf16x8*)(lds + rbx * 4096 + ((wr16 + i) * 2 + 1) * 512 + q128l);
      }
#pragma unroll
    for (int mat = 0; mat < 3; ++mat) {
      const int bb = 8192 + mat * 4096;
#pragma unroll
      for (int j = 0; j < 2; ++j) {
        const bf16x8 bh = *(const bf16x8*)(lds + bb + (wc16 + j) * 512 + q128l);
        const bf16x8 bl = *(const bf16x8*)(lds + bb + 2048 + (wc16 + j) * 512 + q128l);
#pragma unroll
        for (int rbx = 0; rbx < 2; ++rbx)
#pragma unroll
          for (int i = 0; i < 2; ++i) {
            floatx4& a = (mat == 0) ? aq[rbx][i][j]
                       : (mat == 1) ? ak_[rbx][i][j] : av_[rbx][i][j];
            fma3(a, ah[rbx][i], al[rbx][i], bh, bl);
          }
      }
    }
    __syncthreads();
  }
#pragma unroll
  for (int rbx = 0; rbx < 2; ++rbx) {
    const int r0 = (rb0 + rbx) * 64;
    const int b = r0 >> 10;
    const int n0 = r0 & 1023;
#pragma unroll
    for (int j = 0; j < 2; ++j) {
      const int c = c0 + wc + j * 16 + l15;
      if (c < H) {
        const size_t rbw = (((size_t)(b * H + c)) << 10) + n0 + wr + quad * 4;
#pragma unroll
        for (int i = 0; i < 2; ++i) {
          Pk4 pq, pk;
#pragma unroll
          for (int r = 0; r < 4; ++r) {
            pq.b[r] = (bf16_t)aq[rbx][i][j][r];
            pk.b[r] = (bf16_t)(ak_[rbx][i][j][r] * av_[rbx][i][j][r]);
          }
          *(uint2*)(qtb + rbw + i * 16) = pq.u;
          *(uint2*)(kvb + rbw + i * 16) = pk.u;
        }
      }
    }
  }
}

// ---------------------------------------------------------------- GEMM 2 (2-term MFMA): h += prod @ Wo
// one block per 64-row strip, all 256 output cols; prod is bf16 (bit-identical path)
// r4: T14 async-split staging -- dbuf'd 5KB tile, issue kt+1 global load to regs
// BEFORE kt's barrier, ds_write after compute; ONE barrier per kt.
__global__ __launch_bounds__(256) void k_mix(const bf16_t* __restrict__ pv, int H, int KT,
    const bf16_t* __restrict__ WoF, bf16_t* __restrict__ hsh) {
  __shared__ float smem[4352];             // staging 2x64x40 bf16 (10240B) / epilogue 64x68 fp32
  bf16_t* lsm = (bf16_t*)smem;
  const int r0 = blockIdx.x * 64;
  const int t = threadIdx.x;
  const int lane = t & 63, wave = t >> 6;
  const int l15 = lane & 15, quad = lane >> 4;
  const int b = r0 >> 10, n0 = r0 & 1023;
  const int wr = (wave & 1) * 32, wh = wave >> 1;
  const int q128l = quad * 128 + l15 * 8;
  floatx4 acc[2][8] = {};                  // [i][j]: rows wr+i*16, col tile wh*8+j
  const int cl = t >> 3, n8 = (t & 7) * 8;
  {                                        // prologue: load + write kt=0 into buf0
    U4 val;
    val.u = make_uint4(0, 0, 0, 0);
    if (cl < H)
      val.u = *(const uint4*)(pv + ((((size_t)(b * H + cl)) << 10) + n0 + n8));
#pragma unroll
    for (int u = 0; u < 8; ++u) lsm[(n8 + u) * 40 + cl] = val.b[u];
  }
  for (int kt = 0; kt < KT; ++kt) {
    const int cur = kt & 1;
    const bool have = (kt + 1 < KT);
    U4 nxt;
    nxt.u = make_uint4(0, 0, 0, 0);
    if (have) {                            // issue-early: hides under this kt's MFMA
      const int c = (kt + 1) * 32 + cl;
      if (c < H)
        nxt.u = *(const uint4*)(pv + ((((size_t)(b * H + c)) << 10) + n0 + n8));
    }
    __syncthreads();                       // buf[cur] (written prev iter) visible
    const bf16_t* Ls = lsm + cur * 2560;
    const bf16x8 ah0 = *(const bf16x8*)(Ls + (wr + l15) * 40 + quad * 8);
    const bf16x8 ah1 = *(const bf16x8*)(Ls + (wr + 16 + l15) * 40 + quad * 8);
#pragma unroll
    for (int j = 0; j < 8; ++j) {
      const int jj = wh * 8 + j;           // global 16-col tile 0..15
      const int dt = jj >> 2, dgrp = jj & 3;
      const bf16_t* Bb = WoF + (size_t)(dt * 12 + kt) * 4096 + dgrp * 512 + q128l;
      const bf16x8 bh = *(const bf16x8*)Bb;
      const bf16x8 bl = *(const bf16x8*)(Bb + 2048);
      fma2(acc[0][j], ah0, bh, bl);
      fma2(acc[1][j], ah1, bh, bl);
    }
    if (have) {                            // write-late into buf^1 (read next iter)
      bf16_t* Ld = lsm + (cur ^ 1) * 2560;
#pragma unroll
      for (int u = 0; u < 8; ++u) Ld[(n8 + u) * 40 + cl] = nxt.b[u];
    }
  }
  // epilogue: 4 passes over 64-col groups through the shared buffer
  const int nl = t >> 2, q4 = t & 3;
  const int r = r0 + nl;
#pragma unroll
  for (int g = 0; g < 4; ++g) {
    __syncthreads();
    if (wh == (g >> 1)) {
#pragma unroll
      for (int jl = 0; jl < 4; ++jl) {
        const int j = (g & 1) * 4 + jl;
#pragma unroll
        for (int i = 0; i < 2; ++i)
#pragma unroll
          for (int rr = 0; rr < 4; ++rr)
            smem[(wr + i * 16 + quad * 4 + rr) * 68 + jl * 16 + l15] = acc[i][j][rr];
      }
    }
    __syncthreads();
#pragma unroll
    for (int u8 = 0; u8 < 2; ++u8) {
      const int d8 = g * 8 + q4 * 2 + u8;
      const size_t base = hidx(r, d8);
      U4 hi, lo;
      hi.u = *(const uint4*)(hsh + base);
      lo.u = *(const uint4*)(hsh + base + 512);
      U4 oh, ol;
#pragma unroll
      for (int i = 0; i < 8; ++i) {
        const float f = (float)hi.b[i] + (float)lo.b[i] +
                        smem[nl * 68 + (q4 * 2 + u8) * 8 + i];
        const bf16_t h_ = (bf16_t)f;
        oh.b[i] = h_; ol.b[i] = (bf16_t)(f - (float)h_);
      }
      *(uint4*)(hsh + base) = oh.u;
      *(uint4*)(hsh + base + 512) = ol.u;
    }
  }
}

// ---------------------------------------------------------------- GEMM 3 (split MFMA, LDS-DMA): reg_linear + BN partials
// r10: retiled to 64x256 (one strip per block, 1024 blocks) with k_qkv's FROZEN
// single-40KB-buffer stage->sync->compute->sync loop. A staged ONCE per strip
// (was 4x across column-tiles: 393MB -> ~100MB staging). y and BN stats are
// BIT-IDENTICAL to the old 128x64 version: same fragment bytes, same kt=0..7
// fma3 order, same per-row-half reduction chain and (rows0-31)+(rows32-63)
// combination order. Epilogue = k_mix's writer shape + old-k_reg's reader.
__global__ __launch_bounds__(256) void k_reg(const bf16_t* __restrict__ hsh,
    const bf16_t* __restrict__ BtF,
    bf16_t* __restrict__ ybf, float* __restrict__ partial) {
  __shared__ bf16_t lds[20480];            // 40 KB: A 4K elems + B 16K elems
  __shared__ float red[512];               // per-row-half BN column sums
  float* smf = (float*)lds;                // epilogue alias (64x68 fp32 = 17.4KB)
  const int bid = blockIdx.x;              // strip 0..1023
  const int r0 = bid * 64;
  const int t = threadIdx.x;
  const int lane = t & 63, wave = t >> 6;
  const int l15 = lane & 15, quad = lane >> 4;
  const int wr = (wave & 1) * 32, wh = wave >> 1;
  const int wr16 = (wave & 1) * 2;
  const int q128l = quad * 128 + l15 * 8;
  floatx4 acc[2][8] = {};                  // rows wr+i*16, col tile wh*8+j
  for (int kt = 0; kt < 8; ++kt) {
    {
      const bf16_t* A0 = hsh + (size_t)(bid * 8 + kt) * 4096;
#pragma unroll
      for (int s = 0; s < 10; ++s) {
        const int seg = wave * 10 + s;
        const bf16_t* src;
        if (seg < 8) {
          src = A0 + seg * 512;
        } else {
          const int sb = seg - 8;          // 0..31: B tile (sb>>3), segment (sb&7)
          src = BtF + (size_t)((sb >> 3) * 8 + kt) * 4096 + (sb & 7) * 512;
        }
        glds16(src + lane * 8, &lds[seg * 512]);
      }
    }
    __syncthreads();
    bf16x8 ah[2], al[2];
#pragma unroll
    for (int i = 0; i < 2; ++i) {
      ah[i] = *(const bf16x8*)(lds + (wr16 + i) * 1024 + q128l);
      al[i] = *(const bf16x8*)(lds + (wr16 + i) * 1024 + 512 + q128l);
    }
#pragma unroll
    for (int j = 0; j < 8; ++j) {
      const int ct = wh * 2 + (j >> 2), cgrp = j & 3;   // global 16-col tile wh*8+j
      const bf16_t* Bp = lds + 4096 + ct * 4096 + cgrp * 512 + q128l;
      const bf16x8 bh = *(const bf16x8*)Bp;
      const bf16x8 bl = *(const bf16x8*)(Bp + 2048);
#pragma unroll
      for (int i = 0; i < 2; ++i)
        fma3(acc[i][j], ah[i], al[i], bh, bl);
    }
    __syncthreads();
  }
  // BN per-column sums: each wave covers its row half x its 128 cols
#pragma unroll
  for (int j = 0; j < 8; ++j) {
    float s = 0.f;
#pragma unroll
    for (int i = 0; i < 2; ++i)
#pragma unroll
      for (int r = 0; r < 4; ++r)
        s = fmaf(acc[i][j][r], acc[i][j][r], s);
    s += __shfl_down(s, 32);
    s += __shfl_down(s, 16);
    if (lane < 16) red[(wave & 1) * 256 + wh * 128 + j * 16 + lane] = s;
  }
  // epilogue: 4 passes over 64-col groups (k_mix writer / old-k_reg reader)
  const int nl = t >> 2, q4 = t & 3;
#pragma unroll
  for (int g = 0; g < 4; ++g) {
    __syncthreads();
    if (wh == (g >> 1)) {
#pragma unroll
      for (int jl = 0; jl < 4; ++jl) {
        const int j = (g & 1) * 4 + jl;
#pragma unroll
        for (int i = 0; i < 2; ++i)
#pragma unroll
          for (int rr = 0; rr < 4; ++rr)
            smf[(wr + i * 16 + quad * 4 + rr) * 68 + jl * 16 + l15] = acc[i][j][rr];
      }
    }
    __syncthreads();
    const size_t gi = (size_t)(r0 + nl) * 256 + g * 64 + q4 * 16;
#pragma unroll
    for (int u2 = 0; u2 < 2; ++u2) {
      U4 oh, ol;
#pragma unroll
      for (int i = 0; i < 8; ++i) {
        const float f = smf[nl * 68 + q4 * 16 + u2 * 8 + i];
        const bf16_t h_ = (bf16_t)f;
        oh.b[i] = h_; ol.b[i] = (bf16_t)(f - (float)h_);
      }
      *(uint4*)(ybf + gi + u2 * 8) = oh.u;
      *(uint4*)(ybf + kYOFF + gi + u2 * 8) = ol.u;
    }
  }
  // partial: rows0-31 + rows32-63, fixed order (red visible via epilogue barriers)
  partial[(size_t)bid * 256 + t] = red[t] + red[256 + t];
}

// reduce partials over 1024 r-blocks -> stats[128]; 16 blocks, each owns 16 columns
__global__ __launch_bounds__(256) void k_stat(const float* __restrict__ partial,
                                              float* __restrict__ st) {
  __shared__ float sm1[16][16];
  __shared__ float tot[16];
  const int bb = blockIdx.x;               // 0..15
  const int t = threadIdx.x;
  const int col16 = t & 15, rgrp = t >> 4;
  const int c = bb * 16 + col16;
  float s = 0.f;
  for (int r = rgrp; r < 1024; r += 16) s += partial[(size_t)r * 256 + c];
  sm1[rgrp][col16] = s;
  __syncthreads();
  if (t < 16) {
    float v = 0.f;
#pragma unroll
    for (int g = 0; g < 16; ++g) v += sm1[g][t];
    tot[t] = v;
  }
  __syncthreads();
  if (t < 4) {
    const int m = bb * 4 + t;
    st[m] = tot[4 * t];
    st[64 + m] = tot[4 * t + 1] + tot[4 * t + 2] + tot[4 * t + 3];
  }
}

// ---------------------------------------------------------------- BN + norm-activation + residual (layers 0,1)
__global__ void k_bnact(const bf16_t* __restrict__ ybf, const float* __restrict__ stats,
    const float* __restrict__ g0, const float* __restrict__ g1, bf16_t* __restrict__ hsh) {
  const int idx = blockIdx.x * 256 + threadIdx.x;  // r*32 + d8
  const int r = idx >> 5, d8 = idx & 31;
  const int m0 = d8 * 2, m1 = m0 + 1;
  const float i00 = g0[m0] / sqrtf(stats[m0] * (1.0f / 65536.0f) + kEps);
  const float i10 = g1[m0] / sqrtf(stats[64 + m0] * (1.0f / 65536.0f) + kEps);
  const float i01 = g0[m1] / sqrtf(stats[m1] * (1.0f / 65536.0f) + kEps);
  const float i11 = g1[m1] / sqrtf(stats[64 + m1] * (1.0f / 65536.0f) + kEps);
  const size_t ye = (size_t)r * 256 + d8 * 8;
  U4 yh, yl;
  yh.u = *(const uint4*)(ybf + ye);
  yl.u = *(const uint4*)(ybf + kYOFF + ye);
  float yv[8];
#pragma unroll
  for (int i = 0; i < 8; ++i) yv[i] = (float)yh.b[i] + (float)yl.b[i];
  float a[8];
  {
    const float s = yv[0] * i00;
    const float vx = yv[1] * i10, vy = yv[2] * i10, vz = yv[3] * i10;
    const float so = s * sigmoidf(fabsf(s));
    const float vn = sqrtf(fmaf(vx, vx, fmaf(vy, vy, vz * vz)) + kEps);
    const float gv = sigmoidf(vn);
    a[0] = so; a[1] = vx * gv; a[2] = vy * gv; a[3] = vz * gv;
  }
  {
    const float s = yv[4] * i01;
    const float vx = yv[5] * i11, vy = yv[6] * i11, vz = yv[7] * i11;
    const float so = s * sigmoidf(fabsf(s));
    const float vn = sqrtf(fmaf(vx, vx, fmaf(vy, vy, vz * vz)) + kEps);
    const float gv = sigmoidf(vn);
    a[4] = so; a[5] = vx * gv; a[6] = vy * gv; a[7] = vz * gv;
  }
  const size_t base = hidx(r, d8);
  U4 hi, lo;
  hi.u = *(const uint4*)(hsh + base);
  lo.u = *(const uint4*)(hsh + base + 512);
  U4 oh, ol;
#pragma unroll
  for (int i = 0; i < 8; ++i) {
    const float f = (float)hi.b[i] + (float)lo.b[i] + a[i];
    const bf16_t h_ = (bf16_t)f;
    oh.b[i] = h_; ol.b[i] = (bf16_t)(f - (float)h_);
  }
  *(uint4*)(hsh + base) = oh.u;
  *(uint4*)(hsh + base + 512) = ol.u;
}

// ---------------------------------------------------------------- BN + act + residual + POOL (layer 2 only)
// r8: final hsh write + pool re-read eliminated; pooled sums computed in registers.
__global__ __launch_bounds__(256) void k_bnpool(const bf16_t* __restrict__ ybf,
    const float* __restrict__ stats, const float* __restrict__ g0,
    const float* __restrict__ g1, const bf16_t* __restrict__ hsh,
    const float* __restrict__ w_out, float* __restrict__ pp) {
  __shared__ float r0s[256], r1s[256], r2s[256];
  const int t = threadIdx.x;
  const int idx = blockIdx.x * 256 + t;            // r*32 + d8
  const int r = idx >> 5, d8 = idx & 31;
  const int m0 = d8 * 2, m1 = m0 + 1;
  const float i00 = g0[m0] / sqrtf(stats[m0] * (1.0f / 65536.0f) + kEps);
  const float i10 = g1[m0] / sqrtf(stats[64 + m0] * (1.0f / 65536.0f) + kEps);
  const float i01 = g0[m1] / sqrtf(stats[m1] * (1.0f / 65536.0f) + kEps);
  const float i11 = g1[m1] / sqrtf(stats[64 + m1] * (1.0f / 65536.0f) + kEps);
  const size_t ye = (size_t)r * 256 + d8 * 8;
  U4 yh, yl;
  yh.u = *(const uint4*)(ybf + ye);
  yl.u = *(const uint4*)(ybf + kYOFF + ye);
  float yv[8];
#pragma unroll
  for (int i = 0; i < 8; ++i) yv[i] = (float)yh.b[i] + (float)yl.b[i];
  float a[8];
  {
    const float s = yv[0] * i00;
    const float vx = yv[1] * i10, vy = yv[2] * i10, vz = yv[3] * i10;
    const float so = s * sigmoidf(fabsf(s));
    const float vn = sqrtf(fmaf(vx, vx, fmaf(vy, vy, vz * vz)) + kEps);
    const float gv = sigmoidf(vn);
    a[0] = so; a[1] = vx * gv; a[2] = vy * gv; a[3] = vz * gv;
  }
  {
    const float s = yv[4] * i01;
    const float vx = yv[5] * i11, vy = yv[6] * i11, vz = yv[7] * i11;
    const float so = s * sigmoidf(fabsf(s));
    const float vn = sqrtf(fmaf(vx, vx, fmaf(vy, vy, vz * vz)) + kEps);
    const float gv = sigmoidf(vn);
    a[4] = so; a[5] = vx * gv; a[6] = vy * gv; a[7] = vz * gv;
  }
  const size_t base = hidx(r, d8);
  U4 hi, lo;
  hi.u = *(const uint4*)(hsh + base);
  lo.u = *(const uint4*)(hsh + base + 512);
  float f[8];
#pragma unroll
  for (int i = 0; i < 8; ++i) f[i] = (float)hi.b[i] + (float)lo.b[i] + a[i];
  const float w0 = w_out[m0], w1 = w_out[m1];
  r0s[t] = f[1] * w0 + f[5] * w1;
  r1s[t] = f[2] * w0 + f[6] * w1;
  r2s[t] = f[3] * w0 + f[7] * w1;
  __syncthreads();
  for (int s = 128; s > 0; s >>= 1) {
    if (t < s) { r0s[t] += r0s[t + s]; r1s[t] += r1s[t + s]; r2s[t] += r2s[t + s]; }
    __syncthreads();
  }
  if (t == 0) {
    pp[blockIdx.x * 3 + 0] = r0s[0];
    pp[blockIdx.x * 3 + 1] = r1s[0];
    pp[blockIdx.x * 3 + 2] = r2s[0];
  }
}

// final reduce: 128 block-partials per batch -> out[b*3+comp], fixed order
__global__ void k_pool2(const float* __restrict__ pp, float* __restrict__ out) {
  const int t = threadIdx.x;               // 192 threads: t = b*3 + comp
  const int b = t / 3, comp = t % 3;
  float s = 0.f;
  for (int k = 0; k < 128; ++k) s += pp[(size_t)(b * 128 + k) * 3 + comp];
  out[t] = s * (1.0f / kN);
}

} // namespace

extern "C" void kernel_launch(void* const* d_in, const int* in_sizes, int n_in,
                              void* d_out, int out_size, void* d_ws, size_t ws_size,
                              hipStream_t stream) {
  const float* x       = (const float*)d_in[0];
  const float* tok_emb = (const float*)d_in[1];
  const float* Wf      = (const float*)d_in[2];
  const float* wv      = (const float*)d_in[3];
  const float* w_out   = (const float*)d_in[4];

  float* ws    = (float*)d_ws;
  bf16_t* hsh  = (bf16_t*)ws;                          // 16,777,216 fl (2 bf16 planes)
  bf16_t* kvb  = (bf16_t*)(ws + 16777216);             // 11,796,480 fl
  bf16_t* qtb  = (bf16_t*)(ws + 28573696);             // 11,796,480 fl
  bf16_t* prodb = (bf16_t*)(ws + 40370176);            // 11,796,480 fl (region sized 23.6M fl)
  bf16_t* ybf  = prodb;                                // alias: prod dead when y live (split kernels only)
  float*  partial = ws + 40370176 + 20000000;          // 262,144 fl (BN partials / pool partials)
  float*  s0   = ws + 40370176 + 23592960;             //     65,536 fl
  float*  kf3  = s0 + 65536;                           //  1,802,240 fl (3 layers)
  bf16_t* wall3 = (bf16_t*)(kf3 + 1802240);            // 1,474,560 bf16
  bf16_t* WoF3  = wall3 + 1474560;                     // 3 x 196,608 bf16
  bf16_t* BtF3  = WoF3 + 589824;                       // 3 x 131,072 bf16
  float* stats = (float*)(BtF3 + 393216);              // 384 fl
  float* twg   = stats + 384;                          // 1,024 fl (512 float2)

  k_tw<<<2, 256, 0, stream>>>((float2*)twg);
  k_s0<<<kN, 64, 0, stream>>>(tok_emb, Wf, s0);
  k_h0<<<8192, 256, 0, stream>>>(x, wv, s0, hsh);
  k_wqkv3<<<dim3(384, 3), 256, 0, stream>>>(
      (const float*)d_in[5], (const float*)d_in[6], (const float*)d_in[7],
      (const float*)d_in[14], (const float*)d_in[15], (const float*)d_in[16],
      (const float*)d_in[23], (const float*)d_in[24], (const float*)d_in[25], wall3);
  k_wo3<<<dim3(256, 3), 384, 0, stream>>>(
      (const float*)d_in[9], (const float*)d_in[18], (const float*)d_in[27], WoF3);
  k_bt3<<<dim3(256, 3), 256, 0, stream>>>(
      (const float*)d_in[10], (const float*)d_in[11],
      (const float*)d_in[19], (const float*)d_in[20],
      (const float*)d_in[28], (const float*)d_in[29], BtF3);
  k_kf3<<<880, 256, 0, stream>>>(
      (const float*)d_in[8], (const float*)d_in[17], (const float*)d_in[26],
      (const float2*)twg, (float2*)kf3);

  for (int l = 0; l < 3; ++l) {
    const float* g0   = (const float*)d_in[5 + 9 * l + 7];
    const float* g1   = (const float*)d_in[5 + 9 * l + 8];
    const int H = (l == 2) ? 160 : 360;
    const int gy = (H + 63) / 64;                      // 6 or 3
    const int KT = gy * 2;                             // K chunks of 32 (zero-padded weights)
    bf16_t* wall = wall3 + ((l == 2) ? 1179648 : (size_t)l * 589824);
    bf16_t* WoF  = WoF3 + (size_t)l * 196608;
    bf16_t* BtF  = BtF3 + (size_t)l * 131072;
    const float2* kf = (const float2*)kf3 + (size_t)l * 368640;
    float* st = stats + l * 128;

    k_qkv<<<gy * 512, 256, 0, stream>>>(hsh, wall, H, qtb, kvb);
    k_conv<<<16 * H, 256, 0, stream>>>(kvb, qtb, prodb, kf, (const float2*)twg, H);
    k_mix<<<1024, 256, 0, stream>>>(prodb, H, KT, WoF, hsh);
    k_reg<<<1024, 256, 0, stream>>>(hsh, BtF, ybf, partial);
    k_stat<<<16, 256, 0, stream>>>(partial, st);
    if (l < 2) {
      k_bnact<<<8192, 256, 0, stream>>>(ybf, st, g0, g1, hsh);
    } else {
      k_bnpool<<<8192, 256, 0, stream>>>(ybf, st, g0, g1, hsh, w_out, partial);
    }
  }

  k_pool2<<<1, 192, 0, stream>>>(partial, (float*)d_out);
}

// Round 11
// 1010.936 us; speedup vs baseline: 1.0415x; 1.0415x over previous
//
#include <hip/hip_runtime.h>
#include <math.h>

namespace {

typedef __bf16 bf16_t;
typedef bf16_t bf16x8 __attribute__((ext_vector_type(8)));
typedef float floatx4 __attribute__((ext_vector_type(4)));

constexpr int kN = 1024;      // tokens
constexpr int kM = 64;        // multiplicity
constexpr int kP = 64;        // PE dim
constexpr float kEps = 1e-5f;
constexpr int kFN = 1024;     // FFT length
constexpr size_t kYOFF = 16777216;   // ybf plane stride (bf16 elems)

__device__ __forceinline__ float sigmoidf(float v) { return 1.0f / (1.0f + expf(-v)); }

__device__ __forceinline__ floatx4 mfma16(bf16x8 a, bf16x8 b, floatx4 c) {
  return __builtin_amdgcn_mfma_f32_16x16x32_bf16(a, b, c, 0, 0, 0);
}

// 3-term split product: acc += (ah+al)*(bh+bl) dropping al*bl
// REQUIRED for residual-stream h inputs (hi-only h at GEMM input fails: r14, 1.8e-2)
__device__ __forceinline__ void fma3(floatx4& acc, bf16x8 ah, bf16x8 al,
                                     bf16x8 bh, bf16x8 bl) {
  acc = mfma16(ah, bh, acc);
  acc = mfma16(ah, bl, acc);
  acc = mfma16(al, bh, acc);
}

// 2-term: exact split weights x bf16-rounded activation (safe for hyena-branch only)
__device__ __forceinline__ void fma2(floatx4& acc, bf16x8 ah, bf16x8 bh, bf16x8 bl) {
  acc = mfma16(ah, bh, acc);
  acc = mfma16(ah, bl, acc);
}

union U4 { uint4 u; bf16_t b[8]; };
union Pk4 { uint2 u; bf16_t b[4]; };
union Ub2 { uint u; bf16_t b[2]; };

// async 16B/lane global->LDS DMA (wave-uniform LDS base + lane*16 scatter)
// SESSION LEDGER (what is measured-good and what is forbidden):
// r1/r2: k_qkv keeps r0 single-40KB-buffer stage->sync->compute. B-direct-to-reg
//   pollutes vmcnt queue (+9us); 80KB full dbuf loses cross-block overlap (+23us).
// r3/r4: identical k_qkv = 118 vs 142 across sessions with identical bytes ->
//   ~20% clock variance; per-kernel cross-session deltas <20% are suspect.
// r5: NEVER same-line device atomics for stats (131K atomicAdds on 512B = +420us).
// r7/r9: k_mix+k_reg fusion failed correctness twice (0.478/0.485); alias theory
//   falsified; PERMANENTLY SHELVED.
// r10: k_reg 64x256 retile bit-identical but neutral-to-worse -- k_reg is
//   SCHEDULE-bound (dbuf one-barrier-per-kt is the win), not traffic-bound.
__device__ __forceinline__ void glds16(const bf16_t* g, bf16_t* l) {
  __builtin_amdgcn_global_load_lds(
      (const __attribute__((address_space(1))) void*)g,
      (__attribute__((address_space(3))) void*)l, 16, 0, 0);
}

// hsh fragment-major index for (row r, 8-elem group d8), hi plane (lo = +512)
__device__ __forceinline__ size_t hidx(int r, int d8) {
  const int rb = r >> 6, rr = r & 63;
  return (size_t)(rb * 8 + (d8 >> 2)) * 4096 + (rr >> 4) * 1024 + (d8 & 3) * 128 + (rr & 15) * 8;
}

// padded LDS index for FFT work array (breaks small-span bank conflicts)
__device__ __forceinline__ int zi(int i) { return i + (i >> 4); }

__device__ __forceinline__ float2 cadd(float2 a, float2 b) { return {a.x + b.x, a.y + b.y}; }
__device__ __forceinline__ float2 csub(float2 a, float2 b) { return {a.x - b.x, a.y - b.y}; }
__device__ __forceinline__ float2 cmul(float2 a, float2 w) {
  return {a.x * w.x - a.y * w.y, a.x * w.y + a.y * w.x};
}
__device__ __forceinline__ float2 cmulc(float2 a, float2 w) {   // a * conj(w)
  return {a.x * w.x + a.y * w.y, a.y * w.x - a.x * w.y};
}

// ---------------------------------------------------------------- init
__global__ void k_s0(const float* __restrict__ tok_emb, const float* __restrict__ Wf,
                     float* __restrict__ s0) {
  __shared__ float f[kP];
  const int n = blockIdx.x;
  const int t = threadIdx.x;                       // 64 threads
  const int tt = (n == kN - 1) ? 2 : (n & 1);
  const int j = t >> 1;
  const float cexp = (float)(-9.210340371976184 / 64.0);   // -ln(10000)/P
  const float divj = expf((float)(2 * j) * cexp);
  const float ang = (float)n * divj;
  const float pe = (t & 1) ? cosf(ang) : sinf(ang);
  f[t] = pe + tok_emb[tt * kP + t];
  __syncthreads();
  float acc = 0.0f;
#pragma unroll 8
  for (int p = 0; p < kP; ++p) acc = fmaf(f[p], Wf[p * kM + t], acc);
  s0[n * kM + t] = acc;
}

// h planes (fragment-major): irreps m0=d8*2, m1=m0+1 per thread
__global__ void k_h0(const float* __restrict__ x, const float* __restrict__ wv,
                     const float* __restrict__ s0, bf16_t* __restrict__ hsh) {
  const int idx = blockIdx.x * 256 + threadIdx.x;  // r*32 + d8
  const int r = idx >> 5, d8 = idx & 31;
  const int n = r & (kN - 1);
  const int m0 = d8 * 2, m1 = m0 + 1;
  const float w0 = wv[m0], w1 = wv[m1];
  const float x0 = x[r * 3 + 0], x1 = x[r * 3 + 1], x2 = x[r * 3 + 2];
  float f[8];
  f[0] = s0[n * kM + m0]; f[1] = x0 * w0; f[2] = x1 * w0; f[3] = x2 * w0;
  f[4] = s0[n * kM + m1]; f[5] = x0 * w1; f[6] = x1 * w1; f[7] = x2 * w1;
  U4 oh, ol;
#pragma unroll
  for (int i = 0; i < 8; ++i) {
    const bf16_t h_ = (bf16_t)f[i];
    oh.b[i] = h_; ol.b[i] = (bf16_t)(f[i] - (float)h_);
  }
  const size_t base = hidx(r, d8);
  *(uint4*)(hsh + base) = oh.u;
  *(uint4*)(hsh + base + 512) = ol.u;
}

// ---------------------------------------------------------------- weight prep (batched, all 3 layers)
__global__ void k_wqkv3(const float* __restrict__ Wq0, const float* __restrict__ Wk0,
                        const float* __restrict__ Wv0,
                        const float* __restrict__ Wq1, const float* __restrict__ Wk1,
                        const float* __restrict__ Wv1,
                        const float* __restrict__ Wq2, const float* __restrict__ Wk2,
                        const float* __restrict__ Wv2, bf16_t* __restrict__ wall3) {
  const int l = blockIdx.y;
  const int H = (l == 2) ? 160 : 360;
  const int gy = (l == 2) ? 3 : 6;
  const int c = blockIdx.x;    // 0..383
  if (c >= gy * 64) return;
  const int k = threadIdx.x;   // 0..255
  const float* Wq = (l == 0) ? Wq0 : ((l == 1) ? Wq1 : Wq2);
  const float* Wk = (l == 0) ? Wk0 : ((l == 1) ? Wk1 : Wk2);
  const float* Wv = (l == 0) ? Wv0 : ((l == 1) ? Wv1 : Wv2);
  bf16_t* wall = wall3 + ((l == 2) ? 1179648 : (size_t)l * 589824);
  const bool ok = c < H;
  const float w[3] = {ok ? Wq[k * H + c] : 0.f, ok ? Wk[k * H + c] : 0.f,
                      ok ? Wv[k * H + c] : 0.f};
  const int ct = c >> 6, cgrp = (c >> 4) & 3, cl = c & 15;
  const int kc = k >> 5, quad = (k >> 3) & 3, off = k & 7;
  const size_t base = (size_t)(ct * 8 + kc) * 12288 + cgrp * 512 + quad * 128 + cl * 8 + off;
#pragma unroll
  for (int mat = 0; mat < 3; ++mat) {
    const bf16_t hi = (bf16_t)w[mat];
    wall[base + mat * 4096] = hi;
    wall[base + mat * 4096 + 2048] = (bf16_t)(w[mat] - (float)hi);
  }
}

__global__ void k_wo3(const float* __restrict__ Wo0, const float* __restrict__ Wo1,
                      const float* __restrict__ Wo2, bf16_t* __restrict__ WoF3) {
  const int l = blockIdx.y;
  const int H = (l == 2) ? 160 : 360;
  const float* Wo = (l == 0) ? Wo0 : ((l == 1) ? Wo1 : Wo2);
  bf16_t* WoF = WoF3 + (size_t)l * 196608;
  const int d = blockIdx.x;    // 0..255
  const int c = threadIdx.x;   // 0..383
  const float w = (c < H) ? Wo[c * 256 + d] : 0.f;
  const int dt = d >> 6, dgrp = (d >> 4) & 3, dl = d & 15;
  const int kc = c >> 5, quad = (c >> 3) & 3, off = c & 7;
  const size_t base = (size_t)(dt * 12 + kc) * 4096 + dgrp * 512 + quad * 128 + dl * 8 + off;
  const bf16_t hi = (bf16_t)w;
  WoF[base] = hi;
  WoF[base + 2048] = (bf16_t)(w - (float)hi);
}

__global__ void k_bt3(const float* __restrict__ W00, const float* __restrict__ W10,
                      const float* __restrict__ W01, const float* __restrict__ W11,
                      const float* __restrict__ W02, const float* __restrict__ W12,
                      bf16_t* __restrict__ BtF3) {
  const int l = blockIdx.y;
  const float* W0 = (l == 0) ? W00 : ((l == 1) ? W01 : W02);
  const float* W1 = (l == 0) ? W10 : ((l == 1) ? W11 : W12);
  bf16_t* BtF = BtF3 + (size_t)l * 131072;
  const int col = blockIdx.x, row = threadIdx.x;
  const int k = col >> 2, ck = col & 3, m = row >> 2, cm = row & 3;
  float v = 0.f;
  if (cm == ck) v = (ck == 0 ? W0 : W1)[m * 64 + k];
  const int ct = col >> 6, cgrp = (col >> 4) & 3, cl = col & 15;
  const int kc = row >> 5, quad = (row >> 3) & 3, off = row & 7;
  const size_t base = (size_t)(ct * 8 + kc) * 4096 + cgrp * 512 + quad * 128 + cl * 8 + off;
  const bf16_t hi = (bf16_t)v;
  BtF[base] = hi;
  BtF[base + 2048] = (bf16_t)(v - (float)hi);
}

// ---------------------------------------------------------------- FFT (fused radix-2 pairs)
__global__ void k_tw(float2* __restrict__ twg) {
  const int j = blockIdx.x * 256 + threadIdx.x;
  if (j < kFN / 2) {
    float s, c;
    sincosf(-6.283185307179586f * (float)j / (float)kFN, &s, &c);
    twg[j].x = c; twg[j].y = s;
  }
}

// forward DIF radix-4 step (two radix-2 stages fused), one array
__device__ __forceinline__ void dif_step(float2* z, const float2* tw, int m, int p) {
  const int pm = p & (m - 1);
  const int j = ((p & ~(m - 1)) << 2) | pm;
  const int tm2 = 512 / (2 * m), tm1 = 512 / m;
  const float2 x0 = z[zi(j)], x1 = z[zi(j + m)];
  const float2 x2 = z[zi(j + 2 * m)], x3 = z[zi(j + 3 * m)];
  const float2 w2 = tw[pm * tm2], w2b = tw[(pm + m) * tm2], w1 = tw[pm * tm1];
  const float2 a0 = cadd(x0, x2), a2 = cmul(csub(x0, x2), w2);
  const float2 a1 = cadd(x1, x3), a3 = cmul(csub(x1, x3), w2b);
  z[zi(j)]         = cadd(a0, a1);
  z[zi(j + m)]     = cmul(csub(a0, a1), w1);
  z[zi(j + 2 * m)] = cadd(a2, a3);
  z[zi(j + 3 * m)] = cmul(csub(a2, a3), w1);
}

// inverse DIT radix-4 step (fused), one array
__device__ __forceinline__ void dit_step(float2* z, const float2* tw, int m, int p) {
  const int pm = p & (m - 1);
  const int j = ((p & ~(m - 1)) << 2) | pm;
  const int tm2 = 512 / (2 * m), tm1 = 512 / m;
  const float2 x0 = z[zi(j)], x1 = z[zi(j + m)];
  const float2 x2 = z[zi(j + 2 * m)], x3 = z[zi(j + 3 * m)];
  const float2 w1 = tw[pm * tm1], w2 = tw[pm * tm2], w2b = tw[(pm + m) * tm2];
  const float2 c1 = cmulc(x1, w1), c3 = cmulc(x3, w1);
  const float2 b0 = cadd(x0, c1), b1 = csub(x0, c1);
  const float2 b2 = cadd(x2, c3), b3 = csub(x2, c3);
  const float2 d2 = cmulc(b2, w2), d3 = cmulc(b3, w2b);
  z[zi(j)]         = cadd(b0, d2);
  z[zi(j + 2 * m)] = csub(b0, d2);
  z[zi(j + m)]     = cadd(b1, d3);
  z[zi(j + 3 * m)] = csub(b1, d3);
}

// forward DIF, natural in -> bit-reversed out (single array, for k_kf3)
__device__ void fft_dif(float2* z, const float2* tw) {
  const int p = threadIdx.x;
#pragma unroll
  for (int m = 256; m >= 1; m >>= 2) {
    __syncthreads();
    dif_step(z, tw, m, p);
  }
}

// dual-array PARTIAL transforms for k_conv.
// r4: m=1 (both dirs) + pointwise fused in-register (exact twiddles).
// r5: m=256 fwd level fused with the LOAD (in-register, twiddles from global).
__device__ void fft_dif2_hi(float2* za, float2* zb, const float2* tw) {
  const int p = threadIdx.x;
#pragma unroll
  for (int m = 64; m >= 4; m >>= 2) {
    __syncthreads();
    dif_step(za, tw, m, p);
    dif_step(zb, tw, m, p);
  }
}

__device__ void fft_dit_inv2_hi(float2* za, float2* zb, const float2* tw) {
  const int p = threadIdx.x;
#pragma unroll
  for (int m = 4; m <= 256; m <<= 2) {
    __syncthreads();
    dit_step(za, tw, m, p);
    dit_step(zb, tw, m, p);
  }
}

// filter spectra for ALL layers, DIF (bit-reversed) order; 880 blocks
__global__ __launch_bounds__(256) void k_kf3(const float* __restrict__ f0,
    const float* __restrict__ f1, const float* __restrict__ f2,
    const float2* __restrict__ twg, float2* __restrict__ kf3) {
  __shared__ float2 z[kFN + kFN / 16];
  __shared__ float2 tw[kFN / 2];
  const int bid = blockIdx.x;
  const int l = (bid < 360) ? 0 : ((bid < 720) ? 1 : 2);
  const int c = bid - ((l == 0) ? 0 : ((l == 1) ? 360 : 720));
  const int H = (l == 2) ? 160 : 360;
  const float* filt = (l == 0) ? f0 : ((l == 1) ? f1 : f2);
  float2* kf = kf3 + (size_t)l * 368640;
  for (int j = threadIdx.x; j < kFN / 2; j += 256) tw[j] = twg[j];
  for (int n = threadIdx.x; n < kFN; n += 256) {
    z[zi(n)].x = filt[n * H + c];
    z[zi(n)].y = 0.0f;
  }
  fft_dif(z, tw);
  __syncthreads();
  for (int j = threadIdx.x; j < kFN; j += 256) kf[c * kFN + j] = z[zi(j)];
}

// packed circular conv + fused q-product; bf16 in, fp32 FFT, bf16 prod out
// r3: FOUR sequences per block; r4: m=1+pointwise fused; r5: m=256 fused with load.
__global__ __launch_bounds__(256) void k_conv(const bf16_t* __restrict__ kvb,
    const bf16_t* __restrict__ qb, bf16_t* __restrict__ prodb,
    const float2* __restrict__ kf, const float2* __restrict__ twg, int H) {
  __shared__ float2 za[kFN + kFN / 16];
  __shared__ float2 zb[kFN + kFN / 16];
  __shared__ float2 tw[kFN / 2];
  const int blk = blockIdx.x;              // pb*H + c, pb in 0..15 (4 batches each)
  const int c = blk % H;
  const int pb = blk / H;
  const size_t off0 = ((size_t)((4 * pb) * H + c)) << 10;
  const size_t off1 = ((size_t)((4 * pb + 1) * H + c)) << 10;
  const size_t off2 = ((size_t)((4 * pb + 2) * H + c)) << 10;
  const size_t off3 = ((size_t)((4 * pb + 3) * H + c)) << 10;
  for (int j = threadIdx.x; j < kFN / 2; j += 256) tw[j] = twg[j];
  {
    const int p = threadIdx.x;
    float2 xa[4], xb[4];
#pragma unroll
    for (int e = 0; e < 4; ++e) {
      const int idx = p + e * 256;
      xa[e].x = (float)kvb[off0 + idx]; xa[e].y = (float)kvb[off1 + idx];
      xb[e].x = (float)kvb[off2 + idx]; xb[e].y = (float)kvb[off3 + idx];
    }
    // dif m=256: tm2=1, tm1=2; twiddles straight from global (L2-hot)
    const float2 w2 = twg[p], w2b = twg[p + 256], w1 = twg[2 * p];
#pragma unroll
    for (int arr = 0; arr < 2; ++arr) {
      float2* z = arr ? zb : za;
      const float2* x = arr ? xb : xa;
      const float2 a0 = cadd(x[0], x[2]), a2 = cmul(csub(x[0], x[2]), w2);
      const float2 a1 = cadd(x[1], x[3]), a3 = cmul(csub(x[1], x[3]), w2b);
      z[zi(p)]       = cadd(a0, a1);
      z[zi(p + 256)] = cmul(csub(a0, a1), w1);
      z[zi(p + 512)] = cadd(a2, a3);
      z[zi(p + 768)] = cmul(csub(a2, a3), w1);
    }
  }
  fft_dif2_hi(za, zb, tw);                 // levels m=64..4
  __syncthreads();
  {
    const int p = threadIdx.x;             // owns elems 4p..4p+3 of both arrays
    const float2 B0 = kf[c * kFN + 4 * p + 0];
    const float2 B1 = kf[c * kFN + 4 * p + 1];
    const float2 B2 = kf[c * kFN + 4 * p + 2];
    const float2 B3 = kf[c * kFN + 4 * p + 3];
#pragma unroll
    for (int arr = 0; arr < 2; ++arr) {
      float2* z = arr ? zb : za;
      const float2 x0 = z[zi(4 * p)], x1 = z[zi(4 * p + 1)];
      const float2 x2 = z[zi(4 * p + 2)], x3 = z[zi(4 * p + 3)];
      // dif m=1 (w2={1,0}, w2b={0,-1}, w1={1,0} -- exact)
      const float2 a0 = cadd(x0, x2), a2 = csub(x0, x2);
      const float2 a1 = cadd(x1, x3), dd = csub(x1, x3);
      const float2 a3 = {dd.y, -dd.x};
      const float2 y0 = cadd(a0, a1), y1 = csub(a0, a1);
      const float2 y2 = cadd(a2, a3), y3 = csub(a2, a3);
      // pointwise
      const float2 o0 = cmul(y0, B0), o1 = cmul(y1, B1);
      const float2 o2 = cmul(y2, B2), o3 = cmul(y3, B3);
      // dit m=1 (w1={1,0}, w2={1,0}, w2b={0,-1} -- exact)
      const float2 t0 = cadd(o0, o1), t1 = csub(o0, o1);
      const float2 t2 = cadd(o2, o3), t3 = csub(o2, o3);
      const float2 d3 = {-t3.y, t3.x};
      z[zi(4 * p)]     = cadd(t0, t2);
      z[zi(4 * p + 2)] = csub(t0, t2);
      z[zi(4 * p + 1)] = cadd(t1, d3);
      z[zi(4 * p + 3)] = csub(t1, d3);
    }
  }
  fft_dit_inv2_hi(za, zb, tw);             // levels m=4..256
  __syncthreads();
  const float s = 1.0f / (float)kFN;
  for (int n2 = threadIdx.x; n2 < 512; n2 += 256) {
    Ub2 q0, q1, q2, q3, o0, o1, o2, o3;
    q0.u = *(const uint*)(qb + off0 + 2 * n2);
    q1.u = *(const uint*)(qb + off1 + 2 * n2);
    q2.u = *(const uint*)(qb + off2 + 2 * n2);
    q3.u = *(const uint*)(qb + off3 + 2 * n2);
    o0.b[0] = (bf16_t)((za[zi(2 * n2)].x * s) * (float)q0.b[0]);
    o0.b[1] = (bf16_t)((za[zi(2 * n2 + 1)].x * s) * (float)q0.b[1]);
    o1.b[0] = (bf16_t)((za[zi(2 * n2)].y * s) * (float)q1.b[0]);
    o1.b[1] = (bf16_t)((za[zi(2 * n2 + 1)].y * s) * (float)q1.b[1]);
    o2.b[0] = (bf16_t)((zb[zi(2 * n2)].x * s) * (float)q2.b[0]);
    o2.b[1] = (bf16_t)((zb[zi(2 * n2 + 1)].x * s) * (float)q2.b[1]);
    o3.b[0] = (bf16_t)((zb[zi(2 * n2)].y * s) * (float)q3.b[0]);
    o3.b[1] = (bf16_t)((zb[zi(2 * n2 + 1)].y * s) * (float)q3.b[1]);
    *(uint*)(prodb + off0 + 2 * n2) = o0.u;
    *(uint*)(prodb + off1 + 2 * n2) = o1.u;
    *(uint*)(prodb + off2 + 2 * n2) = o2.u;
    *(uint*)(prodb + off3 + 2 * n2) = o3.u;
  }
}

// ---------------------------------------------------------------- GEMM 1 (split MFMA, LDS-DMA): q/k/v
// 128x64 tile (2 rb per block), XCD-swizzled; h enters split hi/lo (fma3); bf16 outputs
// FROZEN r0 structure (measured best): single 40KB buffer, stage->sync->compute->sync.
__global__ __launch_bounds__(256) void k_qkv(const bf16_t* __restrict__ hsh,
    const bf16_t* __restrict__ wall, int H,
    bf16_t* __restrict__ qtb, bf16_t* __restrict__ kvb) {
  __shared__ bf16_t lds[20480];            // 40 KB: A0 8K + A1 8K + B 24K
  const int gy = (H + 63) >> 6;
  const int bid = blockIdx.x;
  const int xcd = bid & 7, sseq = bid >> 3;
  const int ct = sseq % gy;
  const int rb2 = (sseq / gy) * 8 + xcd;
  const int rb0 = rb2 * 2, rb1 = rb0 + 1;
  const int t = threadIdx.x;
  const int lane = t & 63, wave = t >> 6;
  const int l15 = lane & 15, quad = lane >> 4;
  const int c0 = ct * 64;
  const int wr = (wave & 1) * 32, wc = (wave >> 1) * 32;
  const int wr16 = (wave & 1) * 2, wc16 = (wave >> 1) * 2;
  const int q128l = quad * 128 + l15 * 8;
  floatx4 aq[2][2][2] = {}, ak_[2][2][2] = {}, av_[2][2][2] = {};   // [rbx][i][j]
  for (int kt = 0; kt < 8; ++kt) {
    {
      const bf16_t* A0 = hsh + (size_t)(rb0 * 8 + kt) * 4096;
      const bf16_t* A1 = hsh + (size_t)(rb1 * 8 + kt) * 4096;
      const bf16_t* Bs = wall + (size_t)(ct * 8 + kt) * 12288;
#pragma unroll
      for (int s = 0; s < 10; ++s) {
        const int seg = wave * 10 + s;
        const bf16_t* src = (seg < 8) ? (A0 + seg * 512)
                          : (seg < 16) ? (A1 + (seg - 8) * 512)
                                       : (Bs + (seg - 16) * 512);
        glds16(src + lane * 8, &lds[seg * 512]);
      }
    }
    __syncthreads();
    bf16x8 ah[2][2], al[2][2];             // [rbx][i]
#pragma unroll
    for (int rbx = 0; rbx < 2; ++rbx)
#pragma unroll
      for (int i = 0; i < 2; ++i) {
        ah[rbx][i] = *(const bf16x8*)(lds + rbx * 4096 + ((wr16 + i) * 2 + 0) * 512 + q128l);
        al[rbx][i] = *(const bf16x8*)(lds + rbx * 4096 + ((wr16 + i) * 2 + 1) * 512 + q128l);
      }
#pragma unroll
    for (int mat = 0; mat < 3; ++mat) {
      const int bb = 8192 + mat * 4096;
#pragma unroll
      for (int j = 0; j < 2; ++j) {
        const bf16x8 bh = *(const bf16x8*)(lds + bb + (wc16 + j) * 512 + q128l);
        const bf16x8 bl = *(const bf16x8*)(lds + bb + 2048 + (wc16 + j) * 512 + q128l);
#pragma unroll
        for (int rbx = 0; rbx < 2; ++rbx)
#pragma unroll
          for (int i = 0; i < 2; ++i) {
            floatx4& a = (mat == 0) ? aq[rbx][i][j]
                       : (mat == 1) ? ak_[rbx][i][j] : av_[rbx][i][j];
            fma3(a, ah[rbx][i], al[rbx][i], bh, bl);
          }
      }
    }
    __syncthreads();
  }
#pragma unroll
  for (int rbx = 0; rbx < 2; ++rbx) {
    const int r0 = (rb0 + rbx) * 64;
    const int b = r0 >> 10;
    const int n0 = r0 & 1023;
#pragma unroll
    for (int j = 0; j < 2; ++j) {
      const int c = c0 + wc + j * 16 + l15;
      if (c < H) {
        const size_t rbw = (((size_t)(b * H + c)) << 10) + n0 + wr + quad * 4;
#pragma unroll
        for (int i = 0; i < 2; ++i) {
          Pk4 pq, pk;
#pragma unroll
          for (int r = 0; r < 4; ++r) {
            pq.b[r] = (bf16_t)aq[rbx][i][j][r];
            pk.b[r] = (bf16_t)(ak_[rbx][i][j][r] * av_[rbx][i][j][r]);
          }
          *(uint2*)(qtb + rbw + i * 16) = pq.u;
          *(uint2*)(kvb + rbw + i * 16) = pk.u;
        }
      }
    }
  }
}

// ---------------------------------------------------------------- GEMM 2 (2-term MFMA): h += prod @ Wo
// one block per 64-row strip, all 256 output cols; prod is bf16 (bit-identical path)
// r4: T14 async-split staging -- dbuf'd 5KB tile, issue kt+1 global load to regs
// BEFORE kt's barrier, ds_write after compute; ONE barrier per kt.
__global__ __launch_bounds__(256) void k_mix(const bf16_t* __restrict__ pv, int H, int KT,
    const bf16_t* __restrict__ WoF, bf16_t* __restrict__ hsh) {
  __shared__ float smem[4352];             // staging 2x64x40 bf16 (10240B) / epilogue 64x68 fp32
  bf16_t* lsm = (bf16_t*)smem;
  const int r0 = blockIdx.x * 64;
  const int t = threadIdx.x;
  const int lane = t & 63, wave = t >> 6;
  const int l15 = lane & 15, quad = lane >> 4;
  const int b = r0 >> 10, n0 = r0 & 1023;
  const int wr = (wave & 1) * 32, wh = wave >> 1;
  const int q128l = quad * 128 + l15 * 8;
  floatx4 acc[2][8] = {};                  // [i][j]: rows wr+i*16, col tile wh*8+j
  const int cl = t >> 3, n8 = (t & 7) * 8;
  {                                        // prologue: load + write kt=0 into buf0
    U4 val;
    val.u = make_uint4(0, 0, 0, 0);
    if (cl < H)
      val.u = *(const uint4*)(pv + ((((size_t)(b * H + cl)) << 10) + n0 + n8));
#pragma unroll
    for (int u = 0; u < 8; ++u) lsm[(n8 + u) * 40 + cl] = val.b[u];
  }
  for (int kt = 0; kt < KT; ++kt) {
    const int cur = kt & 1;
    const bool have = (kt + 1 < KT);
    U4 nxt;
    nxt.u = make_uint4(0, 0, 0, 0);
    if (have) {                            // issue-early: hides under this kt's MFMA
      const int c = (kt + 1) * 32 + cl;
      if (c < H)
        nxt.u = *(const uint4*)(pv + ((((size_t)(b * H + c)) << 10) + n0 + n8));
    }
    __syncthreads();                       // buf[cur] (written prev iter) visible
    const bf16_t* Ls = lsm + cur * 2560;
    const bf16x8 ah0 = *(const bf16x8*)(Ls + (wr + l15) * 40 + quad * 8);
    const bf16x8 ah1 = *(const bf16x8*)(Ls + (wr + 16 + l15) * 40 + quad * 8);
#pragma unroll
    for (int j = 0; j < 8; ++j) {
      const int jj = wh * 8 + j;           // global 16-col tile 0..15
      const int dt = jj >> 2, dgrp = jj & 3;
      const bf16_t* Bb = WoF + (size_t)(dt * 12 + kt) * 4096 + dgrp * 512 + q128l;
      const bf16x8 bh = *(const bf16x8*)Bb;
      const bf16x8 bl = *(const bf16x8*)(Bb + 2048);
      fma2(acc[0][j], ah0, bh, bl);
      fma2(acc[1][j], ah1, bh, bl);
    }
    if (have) {                            // write-late into buf^1 (read next iter)
      bf16_t* Ld = lsm + (cur ^ 1) * 2560;
#pragma unroll
      for (int u = 0; u < 8; ++u) Ld[(n8 + u) * 40 + cl] = nxt.b[u];
    }
  }
  // epilogue: 4 passes over 64-col groups through the shared buffer
  const int nl = t >> 2, q4 = t & 3;
  const int r = r0 + nl;
#pragma unroll
  for (int g = 0; g < 4; ++g) {
    __syncthreads();
    if (wh == (g >> 1)) {
#pragma unroll
      for (int jl = 0; jl < 4; ++jl) {
        const int j = (g & 1) * 4 + jl;
#pragma unroll
        for (int i = 0; i < 2; ++i)
#pragma unroll
          for (int rr = 0; rr < 4; ++rr)
            smem[(wr + i * 16 + quad * 4 + rr) * 68 + jl * 16 + l15] = acc[i][j][rr];
      }
    }
    __syncthreads();
#pragma unroll
    for (int u8 = 0; u8 < 2; ++u8) {
      const int d8 = g * 8 + q4 * 2 + u8;
      const size_t base = hidx(r, d8);
      U4 hi, lo;
      hi.u = *(const uint4*)(hsh + base);
      lo.u = *(const uint4*)(hsh + base + 512);
      U4 oh, ol;
#pragma unroll
      for (int i = 0; i < 8; ++i) {
        const float f = (float)hi.b[i] + (float)lo.b[i] +
                        smem[nl * 68 + (q4 * 2 + u8) * 8 + i];
        const bf16_t h_ = (bf16_t)f;
        oh.b[i] = h_; ol.b[i] = (bf16_t)(f - (float)h_);
      }
      *(uint4*)(hsh + base) = oh.u;
      *(uint4*)(hsh + base + 512) = ol.u;
    }
  }
}

// ---------------------------------------------------------------- GEMM 3 (split MFMA, LDS-DMA): reg_linear + BN partials
// 128x64 tile (2 rb per block), XCD-swizzled; h enters split (fma3); y output as split-bf16
// r2 structure (measured best): full-tile dbuf at 48KB, one barrier/kt. r10 retile
// was bit-identical but neutral-to-worse -- this dbuf schedule is the win.
__global__ __launch_bounds__(256) void k_reg(const bf16_t* __restrict__ hsh,
    const bf16_t* __restrict__ BtF,
    bf16_t* __restrict__ ybf, float* __restrict__ partial) {
  __shared__ float smf[12288];             // 48 KB: 2 x 24KB DMA dbuf / epilogue alias
  __shared__ float red[256];
  bf16_t* lds = (bf16_t*)smf;
  const int bid = blockIdx.x;
  const int xcd = bid & 7, sseq = bid >> 3;
  const int ct = sseq & 3;
  const int rb2 = (sseq >> 2) * 8 + xcd;
  const int rb0 = rb2 * 2, rb1 = rb0 + 1;
  const int t = threadIdx.x;
  const int lane = t & 63, wave = t >> 6;
  const int l15 = lane & 15, quad = lane >> 4;
  const int c0 = ct * 64;
  const int wr = (wave & 1) * 32, wc = (wave >> 1) * 32;
  const int wr16 = (wave & 1) * 2, wc16 = (wave >> 1) * 2;
  const int q128l = quad * 128 + l15 * 8;
  floatx4 acc[2][2][2] = {};               // [rbx][i][j]
  auto stage = [&](int kt, int buf) {
    const bf16_t* A0 = hsh + (size_t)(rb0 * 8 + kt) * 4096;
    const bf16_t* A1 = hsh + (size_t)(rb1 * 8 + kt) * 4096;
    const bf16_t* Bs = BtF + (size_t)(ct * 8 + kt) * 4096;
#pragma unroll
    for (int s = 0; s < 6; ++s) {
      const int seg = wave * 6 + s;
      const bf16_t* src = (seg < 8) ? (A0 + seg * 512)
                        : (seg < 16) ? (A1 + (seg - 8) * 512)
                                     : (Bs + (seg - 16) * 512);
      glds16(src + lane * 8, &lds[buf * 12288 + seg * 512]);
    }
  };
  stage(0, 0);
  __syncthreads();
  for (int kt = 0; kt < 8; ++kt) {
    const int cur = kt & 1;
    if (kt < 7) stage(kt + 1, cur ^ 1);
    const bf16_t* Lb = lds + cur * 12288;
    bf16x8 ah[2][2], al[2][2];
#pragma unroll
    for (int rbx = 0; rbx < 2; ++rbx)
#pragma unroll
      for (int i = 0; i < 2; ++i) {
        ah[rbx][i] = *(const bf16x8*)(Lb + rbx * 4096 + ((wr16 + i) * 2 + 0) * 512 + q128l);
        al[rbx][i] = *(const bf16x8*)(Lb + rbx * 4096 + ((wr16 + i) * 2 + 1) * 512 + q128l);
      }
#pragma unroll
    for (int j = 0; j < 2; ++j) {
      const bf16x8 bh = *(const bf16x8*)(Lb + 8192 + (wc16 + j) * 512 + q128l);
      const bf16x8 bl = *(const bf16x8*)(Lb + 8192 + 2048 + (wc16 + j) * 512 + q128l);
#pragma unroll
      for (int rbx = 0; rbx < 2; ++rbx)
#pragma unroll
        for (int i = 0; i < 2; ++i)
          fma3(acc[rbx][i][j], ah[rbx][i], al[rbx][i], bh, bl);
    }
    __syncthreads();
  }
  // per-column sum of squares, per rb
#pragma unroll
  for (int rbx = 0; rbx < 2; ++rbx)
#pragma unroll
    for (int j = 0; j < 2; ++j) {
      float s = 0.f;
#pragma unroll
      for (int i = 0; i < 2; ++i)
#pragma unroll
        for (int r = 0; r < 4; ++r)
          s = fmaf(acc[rbx][i][j][r], acc[rbx][i][j][r], s);
      s += __shfl_down(s, 32);
      s += __shfl_down(s, 16);
      if (lane < 16) red[rbx * 128 + wave * 32 + j * 16 + lane] = s;
    }
  // epilogue per rb
#pragma unroll
  for (int rbx = 0; rbx < 2; ++rbx) {
    __syncthreads();
#pragma unroll
    for (int i = 0; i < 2; ++i)
#pragma unroll
      for (int j = 0; j < 2; ++j)
#pragma unroll
        for (int r = 0; r < 4; ++r)
          smf[(wr + i * 16 + quad * 4 + r) * 68 + wc + j * 16 + l15] = acc[rbx][i][j][r];
    __syncthreads();
    const int nl = t >> 2, q4 = t & 3;
    const int r0 = (rb0 + rbx) * 64;
    const size_t gi = (size_t)(r0 + nl) * 256 + c0 + q4 * 16;
#pragma unroll
    for (int u2 = 0; u2 < 2; ++u2) {
      U4 oh, ol;
#pragma unroll
      for (int i = 0; i < 8; ++i) {
        const float f = smf[nl * 68 + q4 * 16 + u2 * 8 + i];
        const bf16_t h_ = (bf16_t)f;
        oh.b[i] = h_; ol.b[i] = (bf16_t)(f - (float)h_);
      }
      *(uint4*)(ybf + gi + u2 * 8) = oh.u;
      *(uint4*)(ybf + kYOFF + gi + u2 * 8) = ol.u;
    }
  }
  if (t < 64) {
    const int w0 = (t >= 32) ? 2 : 0;
    const float v0 = red[w0 * 32 + (t & 31)] + red[(w0 + 1) * 32 + (t & 31)];
    const float v1 = red[128 + w0 * 32 + (t & 31)] + red[128 + (w0 + 1) * 32 + (t & 31)];
    partial[(size_t)rb0 * 256 + c0 + t] = v0;   // race-free: one slot per column
    partial[(size_t)rb1 * 256 + c0 + t] = v1;
  }
}

// reduce partials over 1024 r-blocks -> stats[128]; 16 blocks, each owns 16 columns
__global__ __launch_bounds__(256) void k_stat(const float* __restrict__ partial,
                                              float* __restrict__ st) {
  __shared__ float sm1[16][16];
  __shared__ float tot[16];
  const int bb = blockIdx.x;               // 0..15
  const int t = threadIdx.x;
  const int col16 = t & 15, rgrp = t >> 4;
  const int c = bb * 16 + col16;
  float s = 0.f;
  for (int r = rgrp; r < 1024; r += 16) s += partial[(size_t)r * 256 + c];
  sm1[rgrp][col16] = s;
  __syncthreads();
  if (t < 16) {
    float v = 0.f;
#pragma unroll
    for (int g = 0; g < 16; ++g) v += sm1[g][t];
    tot[t] = v;
  }
  __syncthreads();
  if (t < 4) {
    const int m = bb * 4 + t;
    st[m] = tot[4 * t];
    st[64 + m] = tot[4 * t + 1] + tot[4 * t + 2] + tot[4 * t + 3];
  }
}

// ---------------------------------------------------------------- BN + norm-activation + residual (layers 0,1)
__global__ void k_bnact(const bf16_t* __restrict__ ybf, const float* __restrict__ stats,
    const float* __restrict__ g0, const float* __restrict__ g1, bf16_t* __restrict__ hsh) {
  const int idx = blockIdx.x * 256 + threadIdx.x;  // r*32 + d8
  const int r = idx >> 5, d8 = idx & 31;
  const int m0 = d8 * 2, m1 = m0 + 1;
  const float i00 = g0[m0] / sqrtf(stats[m0] * (1.0f / 65536.0f) + kEps);
  const float i10 = g1[m0] / sqrtf(stats[64 + m0] * (1.0f / 65536.0f) + kEps);
  const float i01 = g0[m1] / sqrtf(stats[m1] * (1.0f / 65536.0f) + kEps);
  const float i11 = g1[m1] / sqrtf(stats[64 + m1] * (1.0f / 65536.0f) + kEps);
  const size_t ye = (size_t)r * 256 + d8 * 8;
  U4 yh, yl;
  yh.u = *(const uint4*)(ybf + ye);
  yl.u = *(const uint4*)(ybf + kYOFF + ye);
  float yv[8];
#pragma unroll
  for (int i = 0; i < 8; ++i) yv[i] = (float)yh.b[i] + (float)yl.b[i];
  float a[8];
  {
    const float s = yv[0] * i00;
    const float vx = yv[1] * i10, vy = yv[2] * i10, vz = yv[3] * i10;
    const float so = s * sigmoidf(fabsf(s));
    const float vn = sqrtf(fmaf(vx, vx, fmaf(vy, vy, vz * vz)) + kEps);
    const float gv = sigmoidf(vn);
    a[0] = so; a[1] = vx * gv; a[2] = vy * gv; a[3] = vz * gv;
  }
  {
    const float s = yv[4] * i01;
    const float vx = yv[5] * i11, vy = yv[6] * i11, vz = yv[7] * i11;
    const float so = s * sigmoidf(fabsf(s));
    const float vn = sqrtf(fmaf(vx, vx, fmaf(vy, vy, vz * vz)) + kEps);
    const float gv = sigmoidf(vn);
    a[4] = so; a[5] = vx * gv; a[6] = vy * gv; a[7] = vz * gv;
  }
  const size_t base = hidx(r, d8);
  U4 hi, lo;
  hi.u = *(const uint4*)(hsh + base);
  lo.u = *(const uint4*)(hsh + base + 512);
  U4 oh, ol;
#pragma unroll
  for (int i = 0; i < 8; ++i) {
    const float f = (float)hi.b[i] + (float)lo.b[i] + a[i];
    const bf16_t h_ = (bf16_t)f;
    oh.b[i] = h_; ol.b[i] = (bf16_t)(f - (float)h_);
  }
  *(uint4*)(hsh + base) = oh.u;
  *(uint4*)(hsh + base + 512) = ol.u;
}

// ---------------------------------------------------------------- BN + act + residual + POOL (layer 2 only)
// r8: final hsh write + pool re-read eliminated; pooled sums computed in registers.
__global__ __launch_bounds__(256) void k_bnpool(const bf16_t* __restrict__ ybf,
    const float* __restrict__ stats, const float* __restrict__ g0,
    const float* __restrict__ g1, const bf16_t* __restrict__ hsh,
    const float* __restrict__ w_out, float* __restrict__ pp) {
  __shared__ float r0s[256], r1s[256], r2s[256];
  const int t = threadIdx.x;
  const int idx = blockIdx.x * 256 + t;            // r*32 + d8
  const int r = idx >> 5, d8 = idx & 31;
  const int m0 = d8 * 2, m1 = m0 + 1;
  const float i00 = g0[m0] / sqrtf(stats[m0] * (1.0f / 65536.0f) + kEps);
  const float i10 = g1[m0] / sqrtf(stats[64 + m0] * (1.0f / 65536.0f) + kEps);
  const float i01 = g0[m1] / sqrtf(stats[m1] * (1.0f / 65536.0f) + kEps);
  const float i11 = g1[m1] / sqrtf(stats[64 + m1] * (1.0f / 65536.0f) + kEps);
  const size_t ye = (size_t)r * 256 + d8 * 8;
  U4 yh, yl;
  yh.u = *(const uint4*)(ybf + ye);
  yl.u = *(const uint4*)(ybf + kYOFF + ye);
  float yv[8];
#pragma unroll
  for (int i = 0; i < 8; ++i) yv[i] = (float)yh.b[i] + (float)yl.b[i];
  float a[8];
  {
    const float s = yv[0] * i00;
    const float vx = yv[1] * i10, vy = yv[2] * i10, vz = yv[3] * i10;
    const float so = s * sigmoidf(fabsf(s));
    const float vn = sqrtf(fmaf(vx, vx, fmaf(vy, vy, vz * vz)) + kEps);
    const float gv = sigmoidf(vn);
    a[0] = so; a[1] = vx * gv; a[2] = vy * gv; a[3] = vz * gv;
  }
  {
    const float s = yv[4] * i01;
    const float vx = yv[5] * i11, vy = yv[6] * i11, vz = yv[7] * i11;
    const float so = s * sigmoidf(fabsf(s));
    const float vn = sqrtf(fmaf(vx, vx, fmaf(vy, vy, vz * vz)) + kEps);
    const float gv = sigmoidf(vn);
    a[4] = so; a[5] = vx * gv; a[6] = vy * gv; a[7] = vz * gv;
  }
  const size_t base = hidx(r, d8);
  U4 hi, lo;
  hi.u = *(const uint4*)(hsh + base);
  lo.u = *(const uint4*)(hsh + base + 512);
  float f[8];
#pragma unroll
  for (int i = 0; i < 8; ++i) f[i] = (float)hi.b[i] + (float)lo.b[i] + a[i];
  const float w0 = w_out[m0], w1 = w_out[m1];
  r0s[t] = f[1] * w0 + f[5] * w1;
  r1s[t] = f[2] * w0 + f[6] * w1;
  r2s[t] = f[3] * w0 + f[7] * w1;
  __syncthreads();
  for (int s = 128; s > 0; s >>= 1) {
    if (t < s) { r0s[t] += r0s[t + s]; r1s[t] += r1s[t + s]; r2s[t] += r2s[t + s]; }
    __syncthreads();
  }
  if (t == 0) {
    pp[blockIdx.x * 3 + 0] = r0s[0];
    pp[blockIdx.x * 3 + 1] = r1s[0];
    pp[blockIdx.x * 3 + 2] = r2s[0];
  }
}

// final reduce: 128 block-partials per batch -> out[b*3+comp], fixed order
__global__ void k_pool2(const float* __restrict__ pp, float* __restrict__ out) {
  const int t = threadIdx.x;               // 192 threads: t = b*3 + comp
  const int b = t / 3, comp = t % 3;
  float s = 0.f;
  for (int k = 0; k < 128; ++k) s += pp[(size_t)(b * 128 + k) * 3 + comp];
  out[t] = s * (1.0f / kN);
}

} // namespace

extern "C" void kernel_launch(void* const* d_in, const int* in_sizes, int n_in,
                              void* d_out, int out_size, void* d_ws, size_t ws_size,
                              hipStream_t stream) {
  const float* x       = (const float*)d_in[0];
  const float* tok_emb = (const float*)d_in[1];
  const float* Wf      = (const float*)d_in[2];
  const float* wv      = (const float*)d_in[3];
  const float* w_out   = (const float*)d_in[4];

  float* ws    = (float*)d_ws;
  bf16_t* hsh  = (bf16_t*)ws;                          // 16,777,216 fl (2 bf16 planes)
  bf16_t* kvb  = (bf16_t*)(ws + 16777216);             // 11,796,480 fl
  bf16_t* qtb  = (bf16_t*)(ws + 28573696);             // 11,796,480 fl
  bf16_t* prodb = (bf16_t*)(ws + 40370176);            // 11,796,480 fl (region sized 23.6M fl)
  bf16_t* ybf  = prodb;                                // alias: prod dead when y live (split kernels only)
  float*  partial = ws + 40370176 + 20000000;          // 262,144 fl (BN partials / pool partials)
  float*  s0   = ws + 40370176 + 23592960;             //     65,536 fl
  float*  kf3  = s0 + 65536;                           //  1,802,240 fl (3 layers)
  bf16_t* wall3 = (bf16_t*)(kf3 + 1802240);            // 1,474,560 bf16
  bf16_t* WoF3  = wall3 + 1474560;                     // 3 x 196,608 bf16
  bf16_t* BtF3  = WoF3 + 589824;                       // 3 x 131,072 bf16
  float* stats = (float*)(BtF3 + 393216);              // 384 fl
  float* twg   = stats + 384;                          // 1,024 fl (512 float2)

  k_tw<<<2, 256, 0, stream>>>((float2*)twg);
  k_s0<<<kN, 64, 0, stream>>>(tok_emb, Wf, s0);
  k_h0<<<8192, 256, 0, stream>>>(x, wv, s0, hsh);
  k_wqkv3<<<dim3(384, 3), 256, 0, stream>>>(
      (const float*)d_in[5], (const float*)d_in[6], (const float*)d_in[7],
      (const float*)d_in[14], (const float*)d_in[15], (const float*)d_in[16],
      (const float*)d_in[23], (const float*)d_in[24], (const float*)d_in[25], wall3);
  k_wo3<<<dim3(256, 3), 384, 0, stream>>>(
      (const float*)d_in[9], (const float*)d_in[18], (const float*)d_in[27], WoF3);
  k_bt3<<<dim3(256, 3), 256, 0, stream>>>(
      (const float*)d_in[10], (const float*)d_in[11],
      (const float*)d_in[19], (const float*)d_in[20],
      (const float*)d_in[28], (const float*)d_in[29], BtF3);
  k_kf3<<<880, 256, 0, stream>>>(
      (const float*)d_in[8], (const float*)d_in[17], (const float*)d_in[26],
      (const float2*)twg, (float2*)kf3);

  for (int l = 0; l < 3; ++l) {
    const float* g0   = (const float*)d_in[5 + 9 * l + 7];
    const float* g1   = (const float*)d_in[5 + 9 * l + 8];
    const int H = (l == 2) ? 160 : 360;
    const int gy = (H + 63) / 64;                      // 6 or 3
    const int KT = gy * 2;                             // K chunks of 32 (zero-padded weights)
    bf16_t* wall = wall3 + ((l == 2) ? 1179648 : (size_t)l * 589824);
    bf16_t* WoF  = WoF3 + (size_t)l * 196608;
    bf16_t* BtF  = BtF3 + (size_t)l * 131072;
    const float2* kf = (const float2*)kf3 + (size_t)l * 368640;
    float* st = stats + l * 128;

    k_qkv<<<gy * 512, 256, 0, stream>>>(hsh, wall, H, qtb, kvb);
    k_conv<<<16 * H, 256, 0, stream>>>(kvb, qtb, prodb, kf, (const float2*)twg, H);
    k_mix<<<1024, 256, 0, stream>>>(prodb, H, KT, WoF, hsh);
    k_reg<<<2048, 256, 0, stream>>>(hsh, BtF, ybf, partial);
    k_stat<<<16, 256, 0, stream>>>(partial, st);
    if (l < 2) {
      k_bnact<<<8192, 256, 0, stream>>>(ybf, st, g0, g1, hsh);
    } else {
      k_bnpool<<<8192, 256, 0, stream>>>(ybf, st, g0, g1, hsh, w_out, partial);
    }
  }

  k_pool2<<<1, 192, 0, stream>>>(partial, (float*)d_out);
}